// Round 1
// baseline (939.992 us; speedup 1.0000x reference)
//
#include <hip/hip_runtime.h>
#include <math.h>

#define NF 40
#define FS 401
#define KPAD 416
#define PSTRIDE 160
#define BB 8
#define LL 160000
#define TOUT 1000
#define TC 16            // frames per block
#define SPT 12           // conv samples per thread
#define NPOS 2801        // 160*(TC-1)+401
#define XTILE 3232
#define YTILE 2816
#define NCHUNK 63

__device__ __forceinline__ float sigm(float x) { return 1.0f / (1.0f + __expf(-x)); }
__device__ __forceinline__ float tanh_fast(float x) { return 1.0f - 2.0f / (__expf(2.0f * x) + 1.0f); }

// ---------------- Kernel 1: fused Gabor conv + |z|^2 + Gaussian pooling ----------------
__global__ __launch_bounds__(256) void gabor_pool_kernel(
    const float* __restrict__ x,
    const float* __restrict__ center_freqs,
    const float* __restrict__ bandwidths,
    const float* __restrict__ pooling_widths,
    float* __restrict__ Xout)   // [B, NF, TOUT]
{
    __shared__ __align__(16) float xs[XTILE];
    __shared__ __align__(16) float ys[YTILE];
    __shared__ __align__(16) float frs[KPAD];
    __shared__ __align__(16) float fis[KPAD];
    __shared__ __align__(16) float wins[KPAD];

    const float PI_F = 3.14159265358979323846f;
    int blk = blockIdx.x;
    int chunk = blk % NCHUNK;
    int bf = blk / NCHUNK;
    int f = bf % NF;
    int b = bf / NF;
    int tau0 = chunk * TC;
    int P0 = tau0 * PSTRIDE - 200;     // first conv position this block
    int tid = threadIdx.x;

    // ---- filter parameters (uniform across block) ----
    const float Z = sqrtf(2.0f * logf(2.0f)) / PI_F;
    float cf = fminf(fmaxf(center_freqs[f], 0.0f), PI_F);
    float bw = fminf(fmaxf(bandwidths[f], 4.0f * Z), 401.0f * Z);
    float denom = 1.0f / (sqrtf(2.0f * PI_F) * bw);
    float pw = fminf(fmaxf(pooling_widths[f], 2.0f / 401.0f), 0.5f);
    float inv2bw2 = 1.0f / (2.0f * bw * bw);
    float invpw = 1.0f / pw;

    // truncation radius: 5 sigma
    int R = (int)floorf(5.0f * bw) + 1;
    if (R > 200) R = 200;
    int k0 = (200 - R) & ~15;
    int span = (201 + R) - k0;
    int kend = k0 + ((span + 15) & ~15);
    if (kend > KPAD) kend = KPAD;

    // ---- build coefficients ----
    for (int k = tid; k < KPAD; k += 256) {
        float fr = 0.f, fi = 0.f, wv = 0.f;
        if (k < FS) {
            float tf = (float)(k - 200);
            float g = denom * expf(-(tf * tf) * inv2bw2);
            float sv, cv;
            sincosf(cf * tf, &sv, &cv);
            fr = g * cv; fi = g * sv;
            float tt = (float)k * (1.0f / 400.0f) - 0.5f;
            float u = tt * invpw;
            wv = expf(-0.5f * u * u);
        }
        frs[k] = fr; fis[k] = fi; wins[k] = wv;
    }

    // ---- load x tile (zero-padded) ----
    int g0 = P0 - 200;
    const float* xb = x + b * LL;
    for (int j = tid; j < XTILE; j += 256) {
        int gi = g0 + j;
        xs[j] = (gi >= 0 && gi < LL) ? xb[gi] : 0.0f;
    }
    __syncthreads();

    // ---- phase 1: conv + energy ----
    int j0 = tid * SPT;
    if (j0 < NPOS) {
        float zr[SPT], zi[SPT];
#pragma unroll
        for (int s = 0; s < SPT; ++s) { zr[s] = 0.f; zi[s] = 0.f; }

        for (int k = k0; k < kend; k += 16) {
            float xv[28];
#pragma unroll
            for (int q = 0; q < 7; ++q)
                *(float4*)(xv + 4 * q) = *(const float4*)(xs + j0 + k + 4 * q);
#pragma unroll
            for (int g = 0; g < 4; ++g) {
                float4 fr4 = *(const float4*)(frs + k + 4 * g);
                float4 fi4 = *(const float4*)(fis + k + 4 * g);
#pragma unroll
                for (int s = 0; s < SPT; ++s) {
                    zr[s] = fmaf(xv[s + 4 * g + 0], fr4.x, zr[s]);
                    zr[s] = fmaf(xv[s + 4 * g + 1], fr4.y, zr[s]);
                    zr[s] = fmaf(xv[s + 4 * g + 2], fr4.z, zr[s]);
                    zr[s] = fmaf(xv[s + 4 * g + 3], fr4.w, zr[s]);
                    zi[s] = fmaf(xv[s + 4 * g + 0], fi4.x, zi[s]);
                    zi[s] = fmaf(xv[s + 4 * g + 1], fi4.y, zi[s]);
                    zi[s] = fmaf(xv[s + 4 * g + 2], fi4.z, zi[s]);
                    zi[s] = fmaf(xv[s + 4 * g + 3], fi4.w, zi[s]);
                }
            }
        }
#pragma unroll
        for (int s = 0; s < SPT; ++s) {
            int j = j0 + s;
            int p = P0 + j;
            float e = zr[s] * zr[s] + zi[s] * zi[s];
            if (j < YTILE) ys[j] = (p >= 0 && p < LL) ? e : 0.0f;
        }
    }
    __syncthreads();

    // ---- phase 2: Gaussian pooling, 16 threads per frame ----
    int ft = tid >> 4;
    int l16 = tid & 15;
    float acc = 0.f;
    int yo = ft * PSTRIDE;
    for (int kw = l16; kw < FS; kw += 16)
        acc += ys[yo + kw] * wins[kw];
#pragma unroll
    for (int off = 8; off > 0; off >>= 1)
        acc += __shfl_down(acc, off, 16);
    int tau = tau0 + ft;
    if (l16 == 0 && tau < TOUT)
        Xout[(b * NF + f) * TOUT + tau] = acc;
}

// ---------------- Kernel 2: PCEN smoother M via wave-per-bin decayed scan ----------------
__global__ __launch_bounds__(256) void pcen_scan_kernel(
    const float* __restrict__ X, float* __restrict__ M)
{
    int wid = (blockIdx.x * 256 + threadIdx.x) >> 6;   // bin
    int lane = threadIdx.x & 63;
    if (wid >= BB * NF) return;
    const float a1 = 0.96f;
    const float a2 = a1 * a1;
    const float a4 = a2 * a2;
    const float a8 = a4 * a4;
    const float a16 = a8 * a8;
    const float a32 = a16 * a16;
    const float ss = 0.04f;
    float al1 = powf(a1, (float)(lane + 1));
    float carry = 0.0f;
    const float* row = X + wid * TOUT;
    float* mrow = M + wid * TOUT;

    for (int c = 0; c < TOUT; c += 64) {
        int t = c + lane;
        float v = (t < TOUT) ? row[t] : 0.0f;
        float y = ss * v;
        float u;
        u = __shfl_up(y, 1, 64);  if (lane >= 1)  y = fmaf(a1, u, y);
        u = __shfl_up(y, 2, 64);  if (lane >= 2)  y = fmaf(a2, u, y);
        u = __shfl_up(y, 4, 64);  if (lane >= 4)  y = fmaf(a4, u, y);
        u = __shfl_up(y, 8, 64);  if (lane >= 8)  y = fmaf(a8, u, y);
        u = __shfl_up(y, 16, 64); if (lane >= 16) y = fmaf(a16, u, y);
        u = __shfl_up(y, 32, 64); if (lane >= 32) y = fmaf(a32, u, y);
        y = fmaf(al1, carry, y);
        carry = __shfl(y, 63, 64);
        if (t < TOUT) mrow[t] = y;
    }
}

// ---------------- Kernel 3: GRU controller + PCEN output, one lane per (bin, t) ----------------
__global__ __launch_bounds__(256) void pcen_ctrl_kernel(
    const float* __restrict__ X, const float* __restrict__ M,
    const float* __restrict__ w_ih, const float* __restrict__ w_hh,
    const float* __restrict__ b_ih, const float* __restrict__ b_hh,
    const float* __restrict__ hw1, const float* __restrict__ hb1,
    const float* __restrict__ hw2, const float* __restrict__ hb2,
    float* __restrict__ out)
{
    __shared__ __align__(16) float s_wih[96];
    __shared__ __align__(16) float s_bih[96];
    __shared__ __align__(16) float s_bhh[96];
    __shared__ __align__(16) float s_whh[96 * 32];
    __shared__ __align__(16) float s_hw1[32 * 32];
    __shared__ __align__(16) float s_hb1[32];
    __shared__ __align__(16) float s_hw2[64];
    __shared__ __align__(16) float s_hb2[2];

    int tid = threadIdx.x;
    for (int i = tid; i < 96; i += 256) { s_wih[i] = w_ih[i]; s_bih[i] = b_ih[i]; s_bhh[i] = b_hh[i]; }
    for (int i = tid; i < 96 * 32; i += 256) s_whh[i] = w_hh[i];
    for (int i = tid; i < 32 * 32; i += 256) s_hw1[i] = hw1[i];
    if (tid < 32) s_hb1[tid] = hb1[tid];
    if (tid < 64) s_hw2[tid] = hw2[tid];
    if (tid < 2)  s_hb2[tid] = hb2[tid];
    __syncthreads();

    int idx = blockIdx.x * 256 + tid;          // bin*TOUT + t
    if (idx >= BB * NF * TOUT) return;
    int t = idx % TOUT;
    float xc = X[idx];
    float xp = (t == 0) ? xc : X[idx - 1];
    float m = M[idx];

    // ---- GRU cell 1 (h = 0) ----
    float h1[32];
#pragma unroll
    for (int j = 0; j < 32; ++j) {
        float ir = fmaf(xp, s_wih[j], s_bih[j]) + s_bhh[j];
        float iz = fmaf(xp, s_wih[32 + j], s_bih[32 + j]) + s_bhh[32 + j];
        float in_ = fmaf(xp, s_wih[64 + j], s_bih[64 + j]);
        float r = sigm(ir);
        float zz = sigm(iz);
        float n = tanh_fast(fmaf(r, s_bhh[64 + j], in_));
        h1[j] = (1.0f - zz) * n;
    }

    // ---- GRU cell 2 ----
    float h2[32];
#pragma unroll
    for (int j = 0; j < 32; ++j) {
        float gr = s_bhh[j], gz = s_bhh[32 + j], gn = s_bhh[64 + j];
#pragma unroll
        for (int k = 0; k < 32; k += 4) {
            float4 wr = *(const float4*)(s_whh + j * 32 + k);
            float4 wz = *(const float4*)(s_whh + (32 + j) * 32 + k);
            float4 wn = *(const float4*)(s_whh + (64 + j) * 32 + k);
            gr = fmaf(h1[k], wr.x, gr); gr = fmaf(h1[k + 1], wr.y, gr);
            gr = fmaf(h1[k + 2], wr.z, gr); gr = fmaf(h1[k + 3], wr.w, gr);
            gz = fmaf(h1[k], wz.x, gz); gz = fmaf(h1[k + 1], wz.y, gz);
            gz = fmaf(h1[k + 2], wz.z, gz); gz = fmaf(h1[k + 3], wz.w, gz);
            gn = fmaf(h1[k], wn.x, gn); gn = fmaf(h1[k + 1], wn.y, gn);
            gn = fmaf(h1[k + 2], wn.z, gn); gn = fmaf(h1[k + 3], wn.w, gn);
        }
        float ir = fmaf(xc, s_wih[j], s_bih[j]) + gr;
        float iz = fmaf(xc, s_wih[32 + j], s_bih[32 + j]) + gz;
        float in_ = fmaf(xc, s_wih[64 + j], s_bih[64 + j]);
        float r = sigm(ir);
        float zz = sigm(iz);
        float n = tanh_fast(fmaf(r, gn, in_));
        h2[j] = fmaf(zz, h1[j] - n, n);   // (1-z)*n + z*h1
    }

    // ---- head: Linear(32,32) -> ReLU -> Linear(32,2) ----
    float l0 = s_hb2[0], l1 = s_hb2[1];
#pragma unroll 4
    for (int i = 0; i < 32; ++i) {
        float acc = s_hb1[i];
#pragma unroll
        for (int k = 0; k < 32; k += 4) {
            float4 w = *(const float4*)(s_hw1 + i * 32 + k);
            acc = fmaf(h2[k], w.x, acc); acc = fmaf(h2[k + 1], w.y, acc);
            acc = fmaf(h2[k + 2], w.z, acc); acc = fmaf(h2[k + 3], w.w, acc);
        }
        acc = fmaxf(acc, 0.0f);
        l0 = fmaf(acc, s_hw2[i], l0);
        l1 = fmaf(acc, s_hw2[32 + i], l1);
    }
    float alpha = sigm(l0);
    float rr = fmaf(0.8f, sigm(l1), 0.2f);

    float md = powf(m + 1e-6f, alpha);
    float val = powf(xc / md + 2.0f, rr) - powf(2.0f, rr);
    out[idx] = val;
}

extern "C" void kernel_launch(void* const* d_in, const int* in_sizes, int n_in,
                              void* d_out, int out_size, void* d_ws, size_t ws_size,
                              hipStream_t stream) {
    const float* x    = (const float*)d_in[0];
    const float* cf   = (const float*)d_in[1];
    const float* bw   = (const float*)d_in[2];
    const float* pw   = (const float*)d_in[3];
    const float* w_ih = (const float*)d_in[4];
    const float* w_hh = (const float*)d_in[5];
    const float* b_ih = (const float*)d_in[6];
    const float* b_hh = (const float*)d_in[7];
    const float* hw1  = (const float*)d_in[8];
    const float* hb1  = (const float*)d_in[9];
    const float* hw2  = (const float*)d_in[10];
    const float* hb2  = (const float*)d_in[11];
    float* out = (float*)d_out;

    float* Xf = (float*)d_ws;                 // [320000] pooled frames
    float* Mf = Xf + BB * NF * TOUT;          // [320000] smoother state

    gabor_pool_kernel<<<dim3(BB * NF * NCHUNK), dim3(256), 0, stream>>>(x, cf, bw, pw, Xf);
    pcen_scan_kernel<<<dim3((BB * NF * 64) / 256), dim3(256), 0, stream>>>(Xf, Mf);
    pcen_ctrl_kernel<<<dim3((BB * NF * TOUT) / 256), dim3(256), 0, stream>>>(
        Xf, Mf, w_ih, w_hh, b_ih, b_hh, hw1, hb1, hw2, hb2, out);
}

// Round 2
// 594.819 us; speedup vs baseline: 1.5803x; 1.5803x over previous
//
#include <hip/hip_runtime.h>
#include <math.h>

#define NF 40
#define FS 401
#define AST 424            // A row stride (f16 elems), 848B: 16B aligned
#define PSTRIDE 160
#define BB 8
#define LL 160000
#define TOUT 1000
#define NTILE 256          // conv positions per block
#define NCHUNKC 625        // conv chunks per b (625*256 = 160000 exact)
#define SLABC 640          // slab columns (255+384+1)
#define SLABST 40          // slab row stride (f16 elems) -> 80B rows, 16B aligned
#define NSLICE 4
#define BPS 2              // batches per slice
#define TCP 16             // frames per pool block
#define NCHUNKP 63

typedef __attribute__((ext_vector_type(8))) _Float16 half8v;
typedef __attribute__((ext_vector_type(4))) float float4v;
typedef _Float16 f16;

__device__ __forceinline__ float sigm(float x) { return 1.0f / (1.0f + __expf(-x)); }
__device__ __forceinline__ float tanh_fast(float x) { return 1.0f - 2.0f / (__expf(2.0f * x) + 1.0f); }

// ---------- prep: Gabor filters -> f16 A[80][AST], rows interleaved (fr0,fi0,fr1,fi1,...) ----------
__global__ __launch_bounds__(256) void prep_filters(
    const float* __restrict__ cf_, const float* __restrict__ bw_, f16* __restrict__ Ag)
{
    const float PI_F = 3.14159265358979323846f;
    int row = blockIdx.x;           // 0..79
    int f = row >> 1, comp = row & 1;
    float Z = sqrtf(2.0f * logf(2.0f)) / PI_F;
    float cf = fminf(fmaxf(cf_[f], 0.0f), PI_F);
    float bw = fminf(fmaxf(bw_[f], 4.0f * Z), 401.0f * Z);
    float denom = 1.0f / (sqrtf(2.0f * PI_F) * bw);
    float inv2 = 1.0f / (2.0f * bw * bw);
    for (int k = threadIdx.x; k < AST; k += 256) {
        float v = 0.0f;
        if (k < FS) {
            float t = (float)(k - 200);
            float g = denom * expf(-(t * t) * inv2);
            float sv, cv;
            sincosf(cf * t, &sv, &cv);
            v = comp ? g * sv : g * cv;
        }
        Ag[row * AST + k] = (f16)v;
    }
}

// ---------- prep: x -> f16 ----------
__global__ __launch_bounds__(256) void convert_x(
    const float* __restrict__ x, f16* __restrict__ xb, int n)
{
    int i = blockIdx.x * 256 + threadIdx.x;
    if (i < n) xb[i] = (f16)x[i];
}

// ---------- conv via MFMA: e[bi][f][p] = zr^2 + zi^2 ----------
__global__ __launch_bounds__(256) void conv_mfma(
    const f16* __restrict__ xb,    // [BPS][LL]
    const f16* __restrict__ Ag,    // [80][AST]
    f16* __restrict__ eb)          // [BPS][NF][LL]
{
    __shared__ f16 slab[SLABC * SLABST];     // 51200 B
    int chunk = blockIdx.x;
    int bi = blockIdx.y;
    int p0 = chunk * NTILE;
    const f16* xs = xb + bi * LL;
    int tid = threadIdx.x;

    // build shifted-window im2col slab: slab[c][kk] = x[p0-200 + c + kk], kk in [0,32)
    int base = p0 - 200;
    for (int idx = tid; idx < SLABC * 32; idx += 256) {
        int c = idx >> 5, kk = idx & 31;
        int g = base + c + kk;
        f16 v = (f16)0.0f;
        if (g >= 0 && g < LL) v = xs[g];
        slab[c * SLABST + kk] = v;
    }
    __syncthreads();

    int wv = tid >> 6, lane = tid & 63, q = lane >> 4, l15 = lane & 15;

    float4v acc[5][4];
#pragma unroll
    for (int t = 0; t < 5; ++t)
#pragma unroll
        for (int s = 0; s < 4; ++s)
            acc[t][s] = (float4v){0.f, 0.f, 0.f, 0.f};

    const f16* aP[5];
    const f16* bP[4];
#pragma unroll
    for (int t = 0; t < 5; ++t) aP[t] = Ag + (16 * t + l15) * AST + 8 * q;
#pragma unroll
    for (int s = 0; s < 4; ++s) bP[s] = slab + (64 * wv + 16 * s + l15) * SLABST + 8 * q;

    // K loop over 13 windows of 32 taps; no barriers, accs in regs
    for (int k = 0; k < 416; k += 32) {
        half8v af[5], bf[4];
#pragma unroll
        for (int t = 0; t < 5; ++t) af[t] = *(const half8v*)(aP[t] + k);
#pragma unroll
        for (int s = 0; s < 4; ++s) bf[s] = *(const half8v*)(bP[s] + k * SLABST);
#pragma unroll
        for (int t = 0; t < 5; ++t)
#pragma unroll
            for (int s = 0; s < 4; ++s)
                acc[t][s] = __builtin_amdgcn_mfma_f32_16x16x32_f16(af[t], bf[s], acc[t][s], 0, 0, 0);
    }

    // epilogue: C rows = quad*4 + reg; interleaved A rows -> regs (0,1)=(re,im) of f0, (2,3) of f0+1
    f16* ebb = eb + bi * NF * LL;
#pragma unroll
    for (int t = 0; t < 5; ++t) {
        int f0 = 8 * t + 2 * q;
#pragma unroll
        for (int s = 0; s < 4; ++s) {
            float4v a = acc[t][s];
            int p = p0 + 64 * wv + 16 * s + l15;
            float e0 = a.x * a.x + a.y * a.y;
            float e1 = a.z * a.z + a.w * a.w;
            ebb[f0 * LL + p] = (f16)e0;
            ebb[(f0 + 1) * LL + p] = (f16)e1;
        }
    }
}

// ---------- Gaussian pooling: X[bi][f][tau] ----------
__global__ __launch_bounds__(256) void pool_kernel(
    const f16* __restrict__ eb, const float* __restrict__ pw_, float* __restrict__ Xout)
{
    __shared__ float ys[2816];
    __shared__ float win[416];
    int chunk = blockIdx.x;   // 63
    int f = blockIdx.y;       // 40
    int bi = blockIdx.z;      // BPS
    int tau0 = chunk * TCP;
    int start = tau0 * PSTRIDE - 200;
    int tid = threadIdx.x;

    float pw = fminf(fmaxf(pw_[f], 2.0f / 401.0f), 0.5f);
    float invpw = 1.0f / pw;
    for (int k = tid; k < 416; k += 256) {
        float w = 0.0f;
        if (k < FS) {
            float tt = (float)k * (1.0f / 400.0f) - 0.5f;
            float u = tt * invpw;
            w = expf(-0.5f * u * u);
        }
        win[k] = w;
    }
    const f16* erow = eb + (bi * NF + f) * LL;
    for (int j = tid; j < 2816; j += 256) {
        int p = start + j;
        ys[j] = (p >= 0 && p < LL) ? (float)erow[p] : 0.0f;
    }
    __syncthreads();

    int ft = tid >> 4, l16 = tid & 15;
    float acc = 0.0f;
    int yo = ft * PSTRIDE;
    for (int kw = l16; kw < FS; kw += 16)
        acc += ys[yo + kw] * win[kw];
#pragma unroll
    for (int off = 8; off > 0; off >>= 1)
        acc += __shfl_down(acc, off, 16);
    int tau = tau0 + ft;
    if (l16 == 0 && tau < TOUT)
        Xout[(bi * NF + f) * TOUT + tau] = acc;
}

// ---------- PCEN smoother M via wave-per-bin decayed scan ----------
__global__ __launch_bounds__(256) void pcen_scan_kernel(
    const float* __restrict__ X, float* __restrict__ M)
{
    int wid = (blockIdx.x * 256 + threadIdx.x) >> 6;   // bin
    int lane = threadIdx.x & 63;
    if (wid >= BB * NF) return;
    const float a1 = 0.96f;
    const float a2 = a1 * a1;
    const float a4 = a2 * a2;
    const float a8 = a4 * a4;
    const float a16 = a8 * a8;
    const float a32 = a16 * a16;
    const float ss = 0.04f;
    float al1 = powf(a1, (float)(lane + 1));
    float carry = 0.0f;
    const float* row = X + wid * TOUT;
    float* mrow = M + wid * TOUT;

    for (int c = 0; c < TOUT; c += 64) {
        int t = c + lane;
        float v = (t < TOUT) ? row[t] : 0.0f;
        float y = ss * v;
        float u;
        u = __shfl_up(y, 1, 64);  if (lane >= 1)  y = fmaf(a1, u, y);
        u = __shfl_up(y, 2, 64);  if (lane >= 2)  y = fmaf(a2, u, y);
        u = __shfl_up(y, 4, 64);  if (lane >= 4)  y = fmaf(a4, u, y);
        u = __shfl_up(y, 8, 64);  if (lane >= 8)  y = fmaf(a8, u, y);
        u = __shfl_up(y, 16, 64); if (lane >= 16) y = fmaf(a16, u, y);
        u = __shfl_up(y, 32, 64); if (lane >= 32) y = fmaf(a32, u, y);
        y = fmaf(al1, carry, y);
        carry = __shfl(y, 63, 64);
        if (t < TOUT) mrow[t] = y;
    }
}

// ---------- GRU controller + PCEN output, one lane per (bin, t) ----------
__global__ __launch_bounds__(256) void pcen_ctrl_kernel(
    const float* __restrict__ X, const float* __restrict__ M,
    const float* __restrict__ w_ih, const float* __restrict__ w_hh,
    const float* __restrict__ b_ih, const float* __restrict__ b_hh,
    const float* __restrict__ hw1, const float* __restrict__ hb1,
    const float* __restrict__ hw2, const float* __restrict__ hb2,
    float* __restrict__ out)
{
    __shared__ __align__(16) float s_wih[96];
    __shared__ __align__(16) float s_bih[96];
    __shared__ __align__(16) float s_bhh[96];
    __shared__ __align__(16) float s_whh[96 * 32];
    __shared__ __align__(16) float s_hw1[32 * 32];
    __shared__ __align__(16) float s_hb1[32];
    __shared__ __align__(16) float s_hw2[64];
    __shared__ __align__(16) float s_hb2[2];

    int tid = threadIdx.x;
    for (int i = tid; i < 96; i += 256) { s_wih[i] = w_ih[i]; s_bih[i] = b_ih[i]; s_bhh[i] = b_hh[i]; }
    for (int i = tid; i < 96 * 32; i += 256) s_whh[i] = w_hh[i];
    for (int i = tid; i < 32 * 32; i += 256) s_hw1[i] = hw1[i];
    if (tid < 32) s_hb1[tid] = hb1[tid];
    if (tid < 64) s_hw2[tid] = hw2[tid];
    if (tid < 2)  s_hb2[tid] = hb2[tid];
    __syncthreads();

    int idx = blockIdx.x * 256 + tid;          // bin*TOUT + t
    if (idx >= BB * NF * TOUT) return;
    int t = idx % TOUT;
    float xc = X[idx];
    float xp = (t == 0) ? xc : X[idx - 1];
    float m = M[idx];

    // GRU cell 1 (h = 0)
    float h1[32];
#pragma unroll
    for (int j = 0; j < 32; ++j) {
        float ir = fmaf(xp, s_wih[j], s_bih[j]) + s_bhh[j];
        float iz = fmaf(xp, s_wih[32 + j], s_bih[32 + j]) + s_bhh[32 + j];
        float in_ = fmaf(xp, s_wih[64 + j], s_bih[64 + j]);
        float r = sigm(ir);
        float zz = sigm(iz);
        float n = tanh_fast(fmaf(r, s_bhh[64 + j], in_));
        h1[j] = (1.0f - zz) * n;
    }

    // GRU cell 2
    float h2[32];
#pragma unroll
    for (int j = 0; j < 32; ++j) {
        float gr = s_bhh[j], gz = s_bhh[32 + j], gn = s_bhh[64 + j];
#pragma unroll
        for (int k = 0; k < 32; k += 4) {
            float4 wr = *(const float4*)(s_whh + j * 32 + k);
            float4 wz = *(const float4*)(s_whh + (32 + j) * 32 + k);
            float4 wn = *(const float4*)(s_whh + (64 + j) * 32 + k);
            gr = fmaf(h1[k], wr.x, gr); gr = fmaf(h1[k + 1], wr.y, gr);
            gr = fmaf(h1[k + 2], wr.z, gr); gr = fmaf(h1[k + 3], wr.w, gr);
            gz = fmaf(h1[k], wz.x, gz); gz = fmaf(h1[k + 1], wz.y, gz);
            gz = fmaf(h1[k + 2], wz.z, gz); gz = fmaf(h1[k + 3], wz.w, gz);
            gn = fmaf(h1[k], wn.x, gn); gn = fmaf(h1[k + 1], wn.y, gn);
            gn = fmaf(h1[k + 2], wn.z, gn); gn = fmaf(h1[k + 3], wn.w, gn);
        }
        float ir = fmaf(xc, s_wih[j], s_bih[j]) + gr;
        float iz = fmaf(xc, s_wih[32 + j], s_bih[32 + j]) + gz;
        float in_ = fmaf(xc, s_wih[64 + j], s_bih[64 + j]);
        float r = sigm(ir);
        float zz = sigm(iz);
        float n = tanh_fast(fmaf(r, gn, in_));
        h2[j] = fmaf(zz, h1[j] - n, n);
    }

    // head
    float l0 = s_hb2[0], l1 = s_hb2[1];
#pragma unroll 4
    for (int i = 0; i < 32; ++i) {
        float acc = s_hb1[i];
#pragma unroll
        for (int k = 0; k < 32; k += 4) {
            float4 w = *(const float4*)(s_hw1 + i * 32 + k);
            acc = fmaf(h2[k], w.x, acc); acc = fmaf(h2[k + 1], w.y, acc);
            acc = fmaf(h2[k + 2], w.z, acc); acc = fmaf(h2[k + 3], w.w, acc);
        }
        acc = fmaxf(acc, 0.0f);
        l0 = fmaf(acc, s_hw2[i], l0);
        l1 = fmaf(acc, s_hw2[32 + i], l1);
    }
    float alpha = sigm(l0);
    float rr = fmaf(0.8f, sigm(l1), 0.2f);

    float md = powf(m + 1e-6f, alpha);
    float val = powf(xc / md + 2.0f, rr) - powf(2.0f, rr);
    out[idx] = val;
}

extern "C" void kernel_launch(void* const* d_in, const int* in_sizes, int n_in,
                              void* d_out, int out_size, void* d_ws, size_t ws_size,
                              hipStream_t stream) {
    const float* x    = (const float*)d_in[0];
    const float* cf   = (const float*)d_in[1];
    const float* bw   = (const float*)d_in[2];
    const float* pw   = (const float*)d_in[3];
    const float* w_ih = (const float*)d_in[4];
    const float* w_hh = (const float*)d_in[5];
    const float* b_ih = (const float*)d_in[6];
    const float* b_hh = (const float*)d_in[7];
    const float* hw1  = (const float*)d_in[8];
    const float* hb1  = (const float*)d_in[9];
    const float* hw2  = (const float*)d_in[10];
    const float* hb2  = (const float*)d_in[11];
    float* out = (float*)d_out;

    // workspace layout (~30.8 MB)
    f16* xb   = (f16*)d_ws;                       // 8*160000 f16
    f16* Ag   = xb + BB * LL;                     // 80*424 f16
    f16* ebuf = Ag + 80 * AST;                    // BPS*40*160000 f16 (reused per slice)
    float* Xf = (float*)(ebuf + (size_t)BPS * NF * LL);
    float* Mf = Xf + BB * NF * TOUT;

    prep_filters<<<dim3(80), dim3(256), 0, stream>>>(cf, bw, Ag);
    convert_x<<<dim3((BB * LL + 255) / 256), dim3(256), 0, stream>>>(x, xb, BB * LL);

    for (int sl = 0; sl < NSLICE; ++sl) {
        conv_mfma<<<dim3(NCHUNKC, BPS), dim3(256), 0, stream>>>(
            xb + (size_t)sl * BPS * LL, Ag, ebuf);
        pool_kernel<<<dim3(NCHUNKP, NF, BPS), dim3(256), 0, stream>>>(
            ebuf, pw, Xf + (size_t)sl * BPS * NF * TOUT);
    }

    pcen_scan_kernel<<<dim3((BB * NF * 64) / 256), dim3(256), 0, stream>>>(Xf, Mf);
    pcen_ctrl_kernel<<<dim3((BB * NF * TOUT) / 256), dim3(256), 0, stream>>>(
        Xf, Mf, w_ih, w_hh, b_ih, b_hh, hw1, hb1, hw2, hb2, out);
}

// Round 3
// 467.478 us; speedup vs baseline: 2.0108x; 1.2724x over previous
//
#include <hip/hip_runtime.h>
#include <math.h>

#define NF 40
#define FS 401
#define AST 424            // A row stride (f16 elems), 848B: 16B aligned
#define PSTRIDE 160
#define BB 8
#define LL 160000
#define TOUT 1000
#define NTILE 256          // conv positions per block
#define NCHUNKC 625        // conv chunks per b (625*256 = 160000 exact)
#define SLABC 640          // slab columns (255+384+1)
#define SLABST 40          // slab row stride (f16 elems) -> 80B rows, 16B aligned
#define NSLICE 4
#define BPS 2              // batches per slice
#define TCP 16             // frames per pool block
#define NCHUNKP 63

typedef __attribute__((ext_vector_type(8))) _Float16 half8v;
typedef __attribute__((ext_vector_type(4))) _Float16 half4v;
typedef __attribute__((ext_vector_type(4))) float float4v;
typedef _Float16 f16;

__device__ __forceinline__ float sigm(float x) { return 1.0f / (1.0f + __expf(-x)); }
__device__ __forceinline__ float tanh_fast(float x) { return 1.0f - 2.0f / (__expf(2.0f * x) + 1.0f); }

// ---------- prep: Gabor filters -> f16 A[80][AST], rows interleaved (fr0,fi0,fr1,fi1,...) ----------
__global__ __launch_bounds__(256) void prep_filters(
    const float* __restrict__ cf_, const float* __restrict__ bw_, f16* __restrict__ Ag)
{
    const float PI_F = 3.14159265358979323846f;
    int row = blockIdx.x;           // 0..79
    int f = row >> 1, comp = row & 1;
    float Z = sqrtf(2.0f * logf(2.0f)) / PI_F;
    float cf = fminf(fmaxf(cf_[f], 0.0f), PI_F);
    float bw = fminf(fmaxf(bw_[f], 4.0f * Z), 401.0f * Z);
    float denom = 1.0f / (sqrtf(2.0f * PI_F) * bw);
    float inv2 = 1.0f / (2.0f * bw * bw);
    for (int k = threadIdx.x; k < AST; k += 256) {
        float v = 0.0f;
        if (k < FS) {
            float t = (float)(k - 200);
            float g = denom * expf(-(t * t) * inv2);
            float sv, cv;
            sincosf(cf * t, &sv, &cv);
            v = comp ? g * sv : g * cv;
        }
        Ag[row * AST + k] = (f16)v;
    }
}

// ---------- prep: x -> f16 ----------
__global__ __launch_bounds__(256) void convert_x(
    const float* __restrict__ x, f16* __restrict__ xb, int n)
{
    int i = blockIdx.x * 256 + threadIdx.x;
    if (i < n) xb[i] = (f16)x[i];
}

// ---------- conv via MFMA: e[bi][f][p] = zr^2 + zi^2 ----------
__global__ __launch_bounds__(256) void conv_mfma(
    const f16* __restrict__ xb,    // [BPS][LL]
    const f16* __restrict__ Ag,    // [80][AST]
    f16* __restrict__ eb)          // [BPS][NF][LL]
{
    __shared__ f16 slab[SLABC * SLABST];     // 51200 B
    int chunk = blockIdx.x;
    int bi = blockIdx.y;
    int p0 = chunk * NTILE;
    const f16* xs = xb + bi * LL;
    int tid = threadIdx.x;

    int base = p0 - 200;
    for (int idx = tid; idx < SLABC * 32; idx += 256) {
        int c = idx >> 5, kk = idx & 31;
        int g = base + c + kk;
        f16 v = (f16)0.0f;
        if (g >= 0 && g < LL) v = xs[g];
        slab[c * SLABST + kk] = v;
    }
    __syncthreads();

    int wv = tid >> 6, lane = tid & 63, q = lane >> 4, l15 = lane & 15;

    float4v acc[5][4];
#pragma unroll
    for (int t = 0; t < 5; ++t)
#pragma unroll
        for (int s = 0; s < 4; ++s)
            acc[t][s] = (float4v){0.f, 0.f, 0.f, 0.f};

    const f16* aP[5];
    const f16* bP[4];
#pragma unroll
    for (int t = 0; t < 5; ++t) aP[t] = Ag + (16 * t + l15) * AST + 8 * q;
#pragma unroll
    for (int s = 0; s < 4; ++s) bP[s] = slab + (64 * wv + 16 * s + l15) * SLABST + 8 * q;

    for (int k = 0; k < 416; k += 32) {
        half8v af[5], bf[4];
#pragma unroll
        for (int t = 0; t < 5; ++t) af[t] = *(const half8v*)(aP[t] + k);
#pragma unroll
        for (int s = 0; s < 4; ++s) bf[s] = *(const half8v*)(bP[s] + k * SLABST);
#pragma unroll
        for (int t = 0; t < 5; ++t)
#pragma unroll
            for (int s = 0; s < 4; ++s)
                acc[t][s] = __builtin_amdgcn_mfma_f32_16x16x32_f16(af[t], bf[s], acc[t][s], 0, 0, 0);
    }

    f16* ebb = eb + bi * NF * LL;
#pragma unroll
    for (int t = 0; t < 5; ++t) {
        int f0 = 8 * t + 2 * q;
#pragma unroll
        for (int s = 0; s < 4; ++s) {
            float4v a = acc[t][s];
            int p = p0 + 64 * wv + 16 * s + l15;
            float e0 = a.x * a.x + a.y * a.y;
            float e1 = a.z * a.z + a.w * a.w;
            ebb[f0 * LL + p] = (f16)e0;
            ebb[(f0 + 1) * LL + p] = (f16)e1;
        }
    }
}

// ---------- Gaussian pooling: X[bi][f][tau] ----------
__global__ __launch_bounds__(256) void pool_kernel(
    const f16* __restrict__ eb, const float* __restrict__ pw_, float* __restrict__ Xout)
{
    __shared__ float ys[2816];
    __shared__ float win[416];
    int chunk = blockIdx.x;
    int f = blockIdx.y;
    int bi = blockIdx.z;
    int tau0 = chunk * TCP;
    int start = tau0 * PSTRIDE - 200;
    int tid = threadIdx.x;

    float pw = fminf(fmaxf(pw_[f], 2.0f / 401.0f), 0.5f);
    float invpw = 1.0f / pw;
    for (int k = tid; k < 416; k += 256) {
        float w = 0.0f;
        if (k < FS) {
            float tt = (float)k * (1.0f / 400.0f) - 0.5f;
            float u = tt * invpw;
            w = expf(-0.5f * u * u);
        }
        win[k] = w;
    }
    const f16* erow = eb + (bi * NF + f) * LL;
    for (int j = tid; j < 2816; j += 256) {
        int p = start + j;
        ys[j] = (p >= 0 && p < LL) ? (float)erow[p] : 0.0f;
    }
    __syncthreads();

    int ft = tid >> 4, l16 = tid & 15;
    float acc = 0.0f;
    int yo = ft * PSTRIDE;
    for (int kw = l16; kw < FS; kw += 16)
        acc += ys[yo + kw] * win[kw];
#pragma unroll
    for (int off = 8; off > 0; off >>= 1)
        acc += __shfl_down(acc, off, 16);
    int tau = tau0 + ft;
    if (l16 == 0 && tau < TOUT)
        Xout[(bi * NF + f) * TOUT + tau] = acc;
}

// ---------- PCEN smoother M via wave-per-bin decayed scan ----------
__global__ __launch_bounds__(256) void pcen_scan_kernel(
    const float* __restrict__ X, float* __restrict__ M)
{
    int wid = (blockIdx.x * 256 + threadIdx.x) >> 6;
    int lane = threadIdx.x & 63;
    if (wid >= BB * NF) return;
    const float a1 = 0.96f;
    const float a2 = a1 * a1;
    const float a4 = a2 * a2;
    const float a8 = a4 * a4;
    const float a16 = a8 * a8;
    const float a32 = a16 * a16;
    const float ss = 0.04f;
    float al1 = powf(a1, (float)(lane + 1));
    float carry = 0.0f;
    const float* row = X + wid * TOUT;
    float* mrow = M + wid * TOUT;

    for (int c = 0; c < TOUT; c += 64) {
        int t = c + lane;
        float v = (t < TOUT) ? row[t] : 0.0f;
        float y = ss * v;
        float u;
        u = __shfl_up(y, 1, 64);  if (lane >= 1)  y = fmaf(a1, u, y);
        u = __shfl_up(y, 2, 64);  if (lane >= 2)  y = fmaf(a2, u, y);
        u = __shfl_up(y, 4, 64);  if (lane >= 4)  y = fmaf(a4, u, y);
        u = __shfl_up(y, 8, 64);  if (lane >= 8)  y = fmaf(a8, u, y);
        u = __shfl_up(y, 16, 64); if (lane >= 16) y = fmaf(a16, u, y);
        u = __shfl_up(y, 32, 64); if (lane >= 32) y = fmaf(a32, u, y);
        y = fmaf(al1, carry, y);
        carry = __shfl(y, 63, 64);
        if (t < TOUT) mrow[t] = y;
    }
}

// ---------- GRU controller + PCEN via MFMA, gates evaluated in C-layout ----------
// Block = 256 threads = 4 waves; each wave handles 16 consecutive (bin,t) instances.
// GRU2 hidden GEMM [96x32 @ 32x16] and head GEMM [32x32 @ 32x16] via mfma_f32_16x16x32_f16.
// C-layout (col=lane&15=instance, row=16t+4q+reg) puts r,z,n for the same j-set in one
// lane's registers, so all gate math is in-register; h1 from GRU1 (same layout) never
// leaves registers. Head-2 (N=2) via per-lane partials + shfl_xor butterfly.
__global__ __launch_bounds__(256) void pcen_ctrl_mfma(
    const float* __restrict__ X, const float* __restrict__ M,
    const float* __restrict__ w_ih, const float* __restrict__ w_hh,
    const float* __restrict__ b_ih, const float* __restrict__ b_hh,
    const float* __restrict__ hw1, const float* __restrict__ hb1,
    const float* __restrict__ hw2, const float* __restrict__ hb2,
    float* __restrict__ out)
{
    __shared__ f16 s_whhA[96 * 40];      // A-source [m][k], stride 40 f16 (80B, 16B-aligned, 2-way banks)
    __shared__ f16 s_w1A[32 * 40];
    __shared__ __align__(16) float4 s_A1[32];  // {wih_r, bih_r+bhh_r, wih_z, bih_z+bhh_z}[j]
    __shared__ __align__(16) float4 s_A2[32];  // {wih_n, bih_n, bhh_n, 0}[j]
    __shared__ float s_hb1[32];
    __shared__ float s_hw2[64];
    __shared__ float s_hb2[2];
    __shared__ f16 sh1[4][16 * 40];      // per-wave h1 [inst][k] f16
    __shared__ f16 sh2[4][16 * 40];
    __shared__ float sxc[4][16], sxp[4][16], smv[4][16];

    int tid = threadIdx.x;
    for (int i = tid; i < 96 * 32; i += 256) {
        int m = i >> 5, k = i & 31;
        s_whhA[m * 40 + k] = (f16)w_hh[i];
    }
    for (int i = tid; i < 32 * 32; i += 256) {
        int m = i >> 5, k = i & 31;
        s_w1A[m * 40 + k] = (f16)hw1[i];
    }
    if (tid < 32) {
        int j = tid;
        s_A1[j] = make_float4(w_ih[j], b_ih[j] + b_hh[j],
                              w_ih[32 + j], b_ih[32 + j] + b_hh[32 + j]);
        s_A2[j] = make_float4(w_ih[64 + j], b_ih[64 + j], b_hh[64 + j], 0.0f);
        s_hb1[j] = hb1[j];
    }
    if (tid < 64) s_hw2[tid] = hw2[tid];
    if (tid < 2)  s_hb2[tid] = hb2[tid];
    __syncthreads();

    int wv = tid >> 6, lane = tid & 63;
    int c = lane & 15, q = lane >> 4;
    int instBase = blockIdx.x * 64 + wv * 16;

    // stage 1: lanes 0..15 load per-instance inputs
    if (lane < 16) {
        int idx = instBase + lane;
        int t = idx % TOUT;
        float xcv = X[idx];
        float xpv = (t == 0) ? xcv : X[idx - 1];
        sxc[wv][lane] = xcv;
        sxp[wv][lane] = xpv;
        smv[wv][lane] = M[idx];
    }
    float xp = sxp[wv][c];
    float xc = sxc[wv][c];
    float mv = smv[wv][c];

    // stage 2: GRU1 in C-layout (h=0, pure elementwise in xp)
    float h1v[8];
#pragma unroll
    for (int jj = 0; jj < 8; ++jj) {
        int j = (jj < 4) ? (4 * q + jj) : (16 + 4 * q + (jj - 4));
        float4 a1 = s_A1[j];
        float4 a2 = s_A2[j];
        float r = sigm(fmaf(xp, a1.x, a1.y));
        float z = sigm(fmaf(xp, a1.z, a1.w));
        float n = tanh_fast(fmaf(xp, a2.x, a2.y) + r * a2.z);
        h1v[jj] = (1.0f - z) * n;
    }

    // stage 3: h1 -> LDS [inst][k] f16 for B-frags (two b64 writes)
    {
        half4v lo = {(f16)h1v[0], (f16)h1v[1], (f16)h1v[2], (f16)h1v[3]};
        half4v hi = {(f16)h1v[4], (f16)h1v[5], (f16)h1v[6], (f16)h1v[7]};
        *(half4v*)(&sh1[wv][c * 40 + 4 * q]) = lo;
        *(half4v*)(&sh1[wv][c * 40 + 16 + 4 * q]) = hi;
    }

    // stage 4: GRU2 hidden GEMM: gh[m=96][n=16] = Whh @ h1^T
    float4v acc[6];
    {
        half8v bf = *(const half8v*)(&sh1[wv][c * 40 + 8 * q]);
#pragma unroll
        for (int t = 0; t < 6; ++t) {
            half8v af = *(const half8v*)(&s_whhA[(16 * t + c) * 40 + 8 * q]);
            acc[t] = __builtin_amdgcn_mfma_f32_16x16x32_f16(af, bf, (float4v){0.f,0.f,0.f,0.f}, 0, 0, 0);
        }
    }

    // stage 5: GRU2 gates in C-layout; h1 still in regs
    float h2v[8];
#pragma unroll
    for (int jj = 0; jj < 8; ++jj) {
        int j = (jj < 4) ? (4 * q + jj) : (16 + 4 * q + (jj - 4));
        int reg = jj & 3;
        float accR = (jj < 4) ? acc[0][reg] : acc[1][reg];
        float accZ = (jj < 4) ? acc[2][reg] : acc[3][reg];
        float accN = (jj < 4) ? acc[4][reg] : acc[5][reg];
        float4 a1 = s_A1[j];
        float4 a2 = s_A2[j];
        float r = sigm(fmaf(xc, a1.x, a1.y) + accR);
        float z = sigm(fmaf(xc, a1.z, a1.w) + accZ);
        float gn = accN + a2.z;
        float n = tanh_fast(fmaf(xc, a2.x, a2.y) + r * gn);
        h2v[jj] = fmaf(z, h1v[jj] - n, n);
    }

    // stage 6: h2 -> LDS
    {
        half4v lo = {(f16)h2v[0], (f16)h2v[1], (f16)h2v[2], (f16)h2v[3]};
        half4v hi = {(f16)h2v[4], (f16)h2v[5], (f16)h2v[6], (f16)h2v[7]};
        *(half4v*)(&sh2[wv][c * 40 + 4 * q]) = lo;
        *(half4v*)(&sh2[wv][c * 40 + 16 + 4 * q]) = hi;
    }

    // stage 7: head GEMM1: hid[m=32][n=16]
    float4v hacc[2];
    {
        half8v bf = *(const half8v*)(&sh2[wv][c * 40 + 8 * q]);
#pragma unroll
        for (int t = 0; t < 2; ++t) {
            half8v af = *(const half8v*)(&s_w1A[(16 * t + c) * 40 + 8 * q]);
            hacc[t] = __builtin_amdgcn_mfma_f32_16x16x32_f16(af, bf, (float4v){0.f,0.f,0.f,0.f}, 0, 0, 0);
        }
    }

    // stage 8: relu + head2 partials (per-lane over its 8 i-values)
    float p0 = 0.f, p1 = 0.f;
#pragma unroll
    for (int jj = 0; jj < 8; ++jj) {
        int i = (jj < 4) ? (4 * q + jj) : (16 + 4 * q + (jj - 4));
        int reg = jj & 3;
        float hv = (jj < 4) ? hacc[0][reg] : hacc[1][reg];
        hv = fmaxf(hv + s_hb1[i], 0.0f);
        p0 = fmaf(hv, s_hw2[i], p0);
        p1 = fmaf(hv, s_hw2[32 + i], p1);
    }
    p0 += __shfl_xor(p0, 16);
    p0 += __shfl_xor(p0, 32);
    p1 += __shfl_xor(p1, 16);
    p1 += __shfl_xor(p1, 32);

    // stage 9: PCEN output (all quads compute redundantly; quad 0 writes)
    float alpha = sigm(p0 + s_hb2[0]);
    float rr = fmaf(0.8f, sigm(p1 + s_hb2[1]), 0.2f);
    float md = __expf(alpha * __logf(mv + 1e-6f));
    float bse = xc / md + 2.0f;
    float val = __expf(rr * __logf(bse)) - __expf(rr * 0.69314718056f);
    if (lane < 16)
        out[instBase + lane] = val;
}

extern "C" void kernel_launch(void* const* d_in, const int* in_sizes, int n_in,
                              void* d_out, int out_size, void* d_ws, size_t ws_size,
                              hipStream_t stream) {
    const float* x    = (const float*)d_in[0];
    const float* cf   = (const float*)d_in[1];
    const float* bw   = (const float*)d_in[2];
    const float* pw   = (const float*)d_in[3];
    const float* w_ih = (const float*)d_in[4];
    const float* w_hh = (const float*)d_in[5];
    const float* b_ih = (const float*)d_in[6];
    const float* b_hh = (const float*)d_in[7];
    const float* hw1  = (const float*)d_in[8];
    const float* hb1  = (const float*)d_in[9];
    const float* hw2  = (const float*)d_in[10];
    const float* hb2  = (const float*)d_in[11];
    float* out = (float*)d_out;

    f16* xb   = (f16*)d_ws;
    f16* Ag   = xb + BB * LL;
    f16* ebuf = Ag + 80 * AST;
    float* Xf = (float*)(ebuf + (size_t)BPS * NF * LL);
    float* Mf = Xf + BB * NF * TOUT;

    prep_filters<<<dim3(80), dim3(256), 0, stream>>>(cf, bw, Ag);
    convert_x<<<dim3((BB * LL + 255) / 256), dim3(256), 0, stream>>>(x, xb, BB * LL);

    for (int sl = 0; sl < NSLICE; ++sl) {
        conv_mfma<<<dim3(NCHUNKC, BPS), dim3(256), 0, stream>>>(
            xb + (size_t)sl * BPS * LL, Ag, ebuf);
        pool_kernel<<<dim3(NCHUNKP, NF, BPS), dim3(256), 0, stream>>>(
            ebuf, pw, Xf + (size_t)sl * BPS * NF * TOUT);
    }

    pcen_scan_kernel<<<dim3((BB * NF * 64) / 256), dim3(256), 0, stream>>>(Xf, Mf);
    pcen_ctrl_mfma<<<dim3((BB * NF * TOUT) / 64), dim3(256), 0, stream>>>(
        Xf, Mf, w_ih, w_hh, b_ih, b_hh, hw1, hb1, hw2, hb2, out);
}

// Round 4
// 293.286 us; speedup vs baseline: 3.2050x; 1.5939x over previous
//
#include <hip/hip_runtime.h>
#include <math.h>

#define NF 40
#define FS 401
#define AST 424            // A row stride (f16 elems), 848B, 16B-aligned rows
#define PSTRIDE 160
#define BB 8
#define LL 160000
#define PADL 256
#define LST 160512         // padded x row stride (f16): 256 + 160000 + 256
#define TOUT 1000
#define NTILE 256          // conv positions per block
#define NCHUNKC 625        // 625*256 = 160000 exact
#define ROWCH 89           // chunks per shifted row (84 used + pad), 89 % 8 == 1
#define ROWST (ROWCH*8)    // 712 f16 per row
#define TCP 16             // frames per pool block
#define NCHUNKP 63

typedef __attribute__((ext_vector_type(8))) _Float16 half8v;
typedef __attribute__((ext_vector_type(4))) _Float16 half4v;
typedef __attribute__((ext_vector_type(4))) float float4v;
typedef _Float16 f16;

__device__ __forceinline__ float sigm(float x) { return 1.0f / (1.0f + __expf(-x)); }
__device__ __forceinline__ float tanh_fast(float x) { return 1.0f - 2.0f / (__expf(2.0f * x) + 1.0f); }

// ---------- prep: Gabor filters -> f16 A[80][AST], rows interleaved (fr0,fi0,fr1,fi1,...) ----------
__global__ __launch_bounds__(256) void prep_filters(
    const float* __restrict__ cf_, const float* __restrict__ bw_, f16* __restrict__ Ag)
{
    const float PI_F = 3.14159265358979323846f;
    int row = blockIdx.x;           // 0..79
    int f = row >> 1, comp = row & 1;
    float Z = sqrtf(2.0f * logf(2.0f)) / PI_F;
    float cf = fminf(fmaxf(cf_[f], 0.0f), PI_F);
    float bw = fminf(fmaxf(bw_[f], 4.0f * Z), 401.0f * Z);
    float denom = 1.0f / (sqrtf(2.0f * PI_F) * bw);
    float inv2 = 1.0f / (2.0f * bw * bw);
    for (int k = threadIdx.x; k < AST; k += 256) {
        float v = 0.0f;
        if (k < FS) {
            float t = (float)(k - 200);
            float g = denom * expf(-(t * t) * inv2);
            float sv, cv;
            sincosf(cf * t, &sv, &cv);
            v = comp ? g * sv : g * cv;
        }
        Ag[row * AST + k] = (f16)v;
    }
}

// ---------- prep: x -> f16 with per-batch zero padding (PADL each side) ----------
__global__ __launch_bounds__(256) void convert_x(
    const float* __restrict__ x, f16* __restrict__ xb)
{
    int i = blockIdx.x * 256 + threadIdx.x;
    if (i >= BB * LST) return;
    int b = i / LST, o = i % LST;
    float v = 0.0f;
    if (o >= PADL && o < PADL + LL) v = x[b * LL + (o - PADL)];
    xb[i] = (f16)v;
}

// ---------- conv via MFMA with 8-shifted-row LDS tile ----------
// Row r (r=0..7), chunk m: rows_[r*ROWST + 8m .. +7] = xpad[pbase + r + 8m .. +7].
// B-frag(pos, k, q) = 16B-aligned read at (pos&7)*ROWST + 8*((pos>>3) + q) + k.
__global__ __launch_bounds__(256) void conv_mfma(
    const f16* __restrict__ xb,    // padded [nb][LST]
    const f16* __restrict__ Ag,    // [80][AST]
    f16* __restrict__ eb)          // [nb][NF][LL]
{
    __shared__ f16 rows_[8 * ROWST];          // 11392 B
    int chunk = blockIdx.x;
    int bi = blockIdx.y;
    int p0 = chunk * NTILE;
    int pbase = PADL + p0 - 200;               // ≡ 0 (mod 8): 56 + 256*chunk
    const f16* xs = xb + (size_t)bi * LST;
    int tid = threadIdx.x;

    // build: 672 chunks (8 rows x 84), each = 5 dword loads + alignbyte + b128 write
    for (int sc = tid; sc < 8 * 84; sc += 256) {
        int r = sc / 84, m = sc - r * 84;
        int s0 = pbase + 8 * m + (r & ~1);     // even f16 index -> 4B-aligned
        const uint* gp = (const uint*)(xs + s0);
        uint v0 = gp[0], v1 = gp[1], v2 = gp[2], v3 = gp[3], v4 = gp[4];
        if (r & 1) {
            v0 = __builtin_amdgcn_alignbyte(v1, v0, 2);
            v1 = __builtin_amdgcn_alignbyte(v2, v1, 2);
            v2 = __builtin_amdgcn_alignbyte(v3, v2, 2);
            v3 = __builtin_amdgcn_alignbyte(v4, v3, 2);
        }
        *(uint4*)(&rows_[r * ROWST + 8 * m]) = make_uint4(v0, v1, v2, v3);
    }
    __syncthreads();

    int wv = tid >> 6, lane = tid & 63, q = lane >> 4, l15 = lane & 15;

    float4v acc[5][4];
#pragma unroll
    for (int t = 0; t < 5; ++t)
#pragma unroll
        for (int s = 0; s < 4; ++s)
            acc[t][s] = (float4v){0.f, 0.f, 0.f, 0.f};

    const f16* aP[5];
    const f16* bP[4];
#pragma unroll
    for (int t = 0; t < 5; ++t) aP[t] = Ag + (16 * t + l15) * AST + 8 * q;
#pragma unroll
    for (int s = 0; s < 4; ++s) {
        int pos = 64 * wv + 16 * s + l15;      // local position 0..255
        bP[s] = rows_ + (pos & 7) * ROWST + 8 * ((pos >> 3) + q);
    }

    for (int k = 0; k < 416; k += 32) {
        half8v af[5], bf[4];
#pragma unroll
        for (int t = 0; t < 5; ++t) af[t] = *(const half8v*)(aP[t] + k);
#pragma unroll
        for (int s = 0; s < 4; ++s) bf[s] = *(const half8v*)(bP[s] + k);
#pragma unroll
        for (int t = 0; t < 5; ++t)
#pragma unroll
            for (int s = 0; s < 4; ++s)
                acc[t][s] = __builtin_amdgcn_mfma_f32_16x16x32_f16(af[t], bf[s], acc[t][s], 0, 0, 0);
    }

    f16* ebb = eb + (size_t)bi * NF * LL;
#pragma unroll
    for (int t = 0; t < 5; ++t) {
        int f0 = 8 * t + 2 * q;
#pragma unroll
        for (int s = 0; s < 4; ++s) {
            float4v a = acc[t][s];
            int p = p0 + 64 * wv + 16 * s + l15;
            float e0 = a.x * a.x + a.y * a.y;
            float e1 = a.z * a.z + a.w * a.w;
            ebb[f0 * LL + p] = (f16)e0;
            ebb[(f0 + 1) * LL + p] = (f16)e1;
        }
    }
}

// ---------- Gaussian pooling: X[bi][f][tau] ----------
__global__ __launch_bounds__(256) void pool_kernel(
    const f16* __restrict__ eb, const float* __restrict__ pw_, float* __restrict__ Xout)
{
    __shared__ float ys[2816];
    __shared__ float win[416];
    int chunk = blockIdx.x;
    int f = blockIdx.y;
    int bi = blockIdx.z;
    int tau0 = chunk * TCP;
    int start = tau0 * PSTRIDE - 200;
    int tid = threadIdx.x;

    float pw = fminf(fmaxf(pw_[f], 2.0f / 401.0f), 0.5f);
    float invpw = 1.0f / pw;
    for (int k = tid; k < 416; k += 256) {
        float w = 0.0f;
        if (k < FS) {
            float tt = (float)k * (1.0f / 400.0f) - 0.5f;
            float u = tt * invpw;
            w = expf(-0.5f * u * u);
        }
        win[k] = w;
    }
    const f16* erow = eb + ((size_t)bi * NF + f) * LL;
    if (start >= 0 && start + 2816 <= LL) {
        // fast path: vectorized f16x8 staging (start ≡ 0 mod 8)
        for (int j = tid; j < 352; j += 256) {
            half8v v = *(const half8v*)(erow + start + 8 * j);
#pragma unroll
            for (int i = 0; i < 8; ++i) ys[8 * j + i] = (float)v[i];
        }
    } else {
        for (int j = tid; j < 2816; j += 256) {
            int p = start + j;
            ys[j] = (p >= 0 && p < LL) ? (float)erow[p] : 0.0f;
        }
    }
    __syncthreads();

    int ft = tid >> 4, l16 = tid & 15;
    float acc = 0.0f;
    int yo = ft * PSTRIDE;
    for (int kw = l16; kw < FS; kw += 16)
        acc += ys[yo + kw] * win[kw];
#pragma unroll
    for (int off = 8; off > 0; off >>= 1)
        acc += __shfl_down(acc, off, 16);
    int tau = tau0 + ft;
    if (l16 == 0 && tau < TOUT)
        Xout[((size_t)bi * NF + f) * TOUT + tau] = acc;
}

// ---------- PCEN smoother M via wave-per-bin decayed scan ----------
__global__ __launch_bounds__(256) void pcen_scan_kernel(
    const float* __restrict__ X, float* __restrict__ M)
{
    int wid = (blockIdx.x * 256 + threadIdx.x) >> 6;
    int lane = threadIdx.x & 63;
    if (wid >= BB * NF) return;
    const float a1 = 0.96f;
    const float a2 = a1 * a1;
    const float a4 = a2 * a2;
    const float a8 = a4 * a4;
    const float a16 = a8 * a8;
    const float a32 = a16 * a16;
    const float ss = 0.04f;
    float al1 = powf(a1, (float)(lane + 1));
    float carry = 0.0f;
    const float* row = X + wid * TOUT;
    float* mrow = M + wid * TOUT;

    for (int c = 0; c < TOUT; c += 64) {
        int t = c + lane;
        float v = (t < TOUT) ? row[t] : 0.0f;
        float y = ss * v;
        float u;
        u = __shfl_up(y, 1, 64);  if (lane >= 1)  y = fmaf(a1, u, y);
        u = __shfl_up(y, 2, 64);  if (lane >= 2)  y = fmaf(a2, u, y);
        u = __shfl_up(y, 4, 64);  if (lane >= 4)  y = fmaf(a4, u, y);
        u = __shfl_up(y, 8, 64);  if (lane >= 8)  y = fmaf(a8, u, y);
        u = __shfl_up(y, 16, 64); if (lane >= 16) y = fmaf(a16, u, y);
        u = __shfl_up(y, 32, 64); if (lane >= 32) y = fmaf(a32, u, y);
        y = fmaf(al1, carry, y);
        carry = __shfl(y, 63, 64);
        if (t < TOUT) mrow[t] = y;
    }
}

// ---------- GRU controller + PCEN via MFMA (C-layout gates) ----------
__global__ __launch_bounds__(256) void pcen_ctrl_mfma(
    const float* __restrict__ X, const float* __restrict__ M,
    const float* __restrict__ w_ih, const float* __restrict__ w_hh,
    const float* __restrict__ b_ih, const float* __restrict__ b_hh,
    const float* __restrict__ hw1, const float* __restrict__ hb1,
    const float* __restrict__ hw2, const float* __restrict__ hb2,
    float* __restrict__ out)
{
    __shared__ f16 s_whhA[96 * 40];
    __shared__ f16 s_w1A[32 * 40];
    __shared__ __align__(16) float4 s_A1[32];
    __shared__ __align__(16) float4 s_A2[32];
    __shared__ float s_hb1[32];
    __shared__ float s_hw2[64];
    __shared__ float s_hb2[2];
    __shared__ f16 sh1[4][16 * 40];
    __shared__ f16 sh2[4][16 * 40];
    __shared__ float sxc[4][16], sxp[4][16], smv[4][16];

    int tid = threadIdx.x;
    for (int i = tid; i < 96 * 32; i += 256) {
        int m = i >> 5, k = i & 31;
        s_whhA[m * 40 + k] = (f16)w_hh[i];
    }
    for (int i = tid; i < 32 * 32; i += 256) {
        int m = i >> 5, k = i & 31;
        s_w1A[m * 40 + k] = (f16)hw1[i];
    }
    if (tid < 32) {
        int j = tid;
        s_A1[j] = make_float4(w_ih[j], b_ih[j] + b_hh[j],
                              w_ih[32 + j], b_ih[32 + j] + b_hh[32 + j]);
        s_A2[j] = make_float4(w_ih[64 + j], b_ih[64 + j], b_hh[64 + j], 0.0f);
        s_hb1[j] = hb1[j];
    }
    if (tid < 64) s_hw2[tid] = hw2[tid];
    if (tid < 2)  s_hb2[tid] = hb2[tid];
    __syncthreads();

    int wv = tid >> 6, lane = tid & 63;
    int c = lane & 15, q = lane >> 4;
    int instBase = blockIdx.x * 64 + wv * 16;

    if (lane < 16) {
        int idx = instBase + lane;
        int t = idx % TOUT;
        float xcv = X[idx];
        float xpv = (t == 0) ? xcv : X[idx - 1];
        sxc[wv][lane] = xcv;
        sxp[wv][lane] = xpv;
        smv[wv][lane] = M[idx];
    }
    float xp = sxp[wv][c];
    float xc = sxc[wv][c];
    float mv = smv[wv][c];

    float h1v[8];
#pragma unroll
    for (int jj = 0; jj < 8; ++jj) {
        int j = (jj < 4) ? (4 * q + jj) : (16 + 4 * q + (jj - 4));
        float4 a1 = s_A1[j];
        float4 a2 = s_A2[j];
        float r = sigm(fmaf(xp, a1.x, a1.y));
        float z = sigm(fmaf(xp, a1.z, a1.w));
        float n = tanh_fast(fmaf(xp, a2.x, a2.y) + r * a2.z);
        h1v[jj] = (1.0f - z) * n;
    }

    {
        half4v lo = {(f16)h1v[0], (f16)h1v[1], (f16)h1v[2], (f16)h1v[3]};
        half4v hi = {(f16)h1v[4], (f16)h1v[5], (f16)h1v[6], (f16)h1v[7]};
        *(half4v*)(&sh1[wv][c * 40 + 4 * q]) = lo;
        *(half4v*)(&sh1[wv][c * 40 + 16 + 4 * q]) = hi;
    }

    float4v acc[6];
    {
        half8v bf = *(const half8v*)(&sh1[wv][c * 40 + 8 * q]);
#pragma unroll
        for (int t = 0; t < 6; ++t) {
            half8v af = *(const half8v*)(&s_whhA[(16 * t + c) * 40 + 8 * q]);
            acc[t] = __builtin_amdgcn_mfma_f32_16x16x32_f16(af, bf, (float4v){0.f,0.f,0.f,0.f}, 0, 0, 0);
        }
    }

    float h2v[8];
#pragma unroll
    for (int jj = 0; jj < 8; ++jj) {
        int j = (jj < 4) ? (4 * q + jj) : (16 + 4 * q + (jj - 4));
        int reg = jj & 3;
        float accR = (jj < 4) ? acc[0][reg] : acc[1][reg];
        float accZ = (jj < 4) ? acc[2][reg] : acc[3][reg];
        float accN = (jj < 4) ? acc[4][reg] : acc[5][reg];
        float4 a1 = s_A1[j];
        float4 a2 = s_A2[j];
        float r = sigm(fmaf(xc, a1.x, a1.y) + accR);
        float z = sigm(fmaf(xc, a1.z, a1.w) + accZ);
        float gn = accN + a2.z;
        float n = tanh_fast(fmaf(xc, a2.x, a2.y) + r * gn);
        h2v[jj] = fmaf(z, h1v[jj] - n, n);
    }

    {
        half4v lo = {(f16)h2v[0], (f16)h2v[1], (f16)h2v[2], (f16)h2v[3]};
        half4v hi = {(f16)h2v[4], (f16)h2v[5], (f16)h2v[6], (f16)h2v[7]};
        *(half4v*)(&sh2[wv][c * 40 + 4 * q]) = lo;
        *(half4v*)(&sh2[wv][c * 40 + 16 + 4 * q]) = hi;
    }

    float4v hacc[2];
    {
        half8v bf = *(const half8v*)(&sh2[wv][c * 40 + 8 * q]);
#pragma unroll
        for (int t = 0; t < 2; ++t) {
            half8v af = *(const half8v*)(&s_w1A[(16 * t + c) * 40 + 8 * q]);
            hacc[t] = __builtin_amdgcn_mfma_f32_16x16x32_f16(af, bf, (float4v){0.f,0.f,0.f,0.f}, 0, 0, 0);
        }
    }

    float p0 = 0.f, p1 = 0.f;
#pragma unroll
    for (int jj = 0; jj < 8; ++jj) {
        int i = (jj < 4) ? (4 * q + jj) : (16 + 4 * q + (jj - 4));
        int reg = jj & 3;
        float hv = (jj < 4) ? hacc[0][reg] : hacc[1][reg];
        hv = fmaxf(hv + s_hb1[i], 0.0f);
        p0 = fmaf(hv, s_hw2[i], p0);
        p1 = fmaf(hv, s_hw2[32 + i], p1);
    }
    p0 += __shfl_xor(p0, 16);
    p0 += __shfl_xor(p0, 32);
    p1 += __shfl_xor(p1, 16);
    p1 += __shfl_xor(p1, 32);

    float alpha = sigm(p0 + s_hb2[0]);
    float rr = fmaf(0.8f, sigm(p1 + s_hb2[1]), 0.2f);
    float md = __expf(alpha * __logf(mv + 1e-6f));
    float bse = xc / md + 2.0f;
    float val = __expf(rr * __logf(bse)) - __expf(rr * 0.69314718056f);
    if (lane < 16)
        out[instBase + lane] = val;
}

extern "C" void kernel_launch(void* const* d_in, const int* in_sizes, int n_in,
                              void* d_out, int out_size, void* d_ws, size_t ws_size,
                              hipStream_t stream) {
    const float* x    = (const float*)d_in[0];
    const float* cf   = (const float*)d_in[1];
    const float* bw   = (const float*)d_in[2];
    const float* pw   = (const float*)d_in[3];
    const float* w_ih = (const float*)d_in[4];
    const float* w_hh = (const float*)d_in[5];
    const float* b_ih = (const float*)d_in[6];
    const float* b_hh = (const float*)d_in[7];
    const float* hw1  = (const float*)d_in[8];
    const float* hb1  = (const float*)d_in[9];
    const float* hw2  = (const float*)d_in[10];
    const float* hb2  = (const float*)d_in[11];
    float* out = (float*)d_out;

    // tier selection: batches-per-slice by available workspace (ws_size is fixed
    // across calls -> identical launch sequence every call, graph-safe)
    const size_t xb_b  = (size_t)BB * LST * 2;
    const size_t ag_b  = (size_t)80 * AST * 2;
    const size_t xm_b  = (size_t)2 * BB * NF * TOUT * 4;
    size_t fixed = xb_b + ag_b + xm_b;
    size_t e_per_batch = (size_t)NF * LL * 2;
    int nb;
    if (ws_size >= fixed + 8 * e_per_batch)      nb = 8;
    else if (ws_size >= fixed + 2 * e_per_batch) nb = 2;
    else                                         nb = 1;
    int nslice = BB / nb;

    f16* xb   = (f16*)d_ws;                         // [BB][LST]
    f16* Ag   = xb + (size_t)BB * LST;              // [80][AST]
    f16* ebuf = Ag + (size_t)80 * AST;              // [nb][NF][LL]
    float* Xf = (float*)(ebuf + (size_t)nb * NF * LL);
    float* Mf = Xf + (size_t)BB * NF * TOUT;

    prep_filters<<<dim3(80), dim3(256), 0, stream>>>(cf, bw, Ag);
    convert_x<<<dim3((BB * LST + 255) / 256), dim3(256), 0, stream>>>(x, xb);

    for (int sl = 0; sl < nslice; ++sl) {
        conv_mfma<<<dim3(NCHUNKC, nb), dim3(256), 0, stream>>>(
            xb + (size_t)sl * nb * LST, Ag, ebuf);
        pool_kernel<<<dim3(NCHUNKP, NF, nb), dim3(256), 0, stream>>>(
            ebuf, pw, Xf + (size_t)sl * nb * NF * TOUT);
    }

    pcen_scan_kernel<<<dim3((BB * NF * 64) / 256), dim3(256), 0, stream>>>(Xf, Mf);
    pcen_ctrl_mfma<<<dim3((BB * NF * TOUT) / 64), dim3(256), 0, stream>>>(
        Xf, Mf, w_ih, w_hh, b_ih, b_hh, hw1, hb1, hw2, hb2, out);
}